// Round 5
// baseline (575.105 us; speedup 1.0000x reference)
//
#include <hip/hip_runtime.h>

#define C_ 256
#define T_ 16
#define H_ 64
#define W_ 64
#define PT 5
#define PH 8
#define PW 8
#define OT 4
#define OH 7
#define OW 7
#define SSCALE (1.0f/16.0f)
#define TSCALE 1.0f
#define CG 32               /* channels per roi block */
#define LROW 66             /* plane row stride: 8B-aligned, 2-way banks max */
#define NOUT (CG * OT * OH * OW)   /* 6272 outputs per block */

typedef float f4v __attribute__((ext_vector_type(4)));
typedef float f2v __attribute__((ext_vector_type(2)));
typedef _Float16 h4v __attribute__((ext_vector_type(4)));
typedef _Float16 h8v __attribute__((ext_vector_type(8)));

// ---------------- transpose+cvt (B,C,T,H,W) f32 -> (B,T,H,W,C) fp16 ----------------
// One block owns the FULL 256-channel extent of 64 thw rows, so every ft line
// (512B = 256ch fp16) is written whole by one wave: no partial-line RFO, no
// cross-XCD line bouncing. Phase A: coalesced 256B reads (16 lanes x f4 per
// c-row, NT). Phase B: wave w stores row t as 64 lanes x h4v = 512B full line.
__global__ __launch_bounds__(256) void transpose_kernel(const float* __restrict__ f,
                                                        _Float16* __restrict__ ft) {
    __shared__ _Float16 tile[64][260];   // 33280 B; [thw][c], pad 260: 8B-aligned rows
    const int THW = T_ * H_ * W_;
    int thw0 = blockIdx.x * 64;
    int b = blockIdx.y;

    int l4 = threadIdx.x & 15;    // thw quad within 64
    int cr = threadIdx.x >> 4;    // 0..15 channel row within band
#pragma unroll 4
    for (int k = 0; k < 16; ++k) {
        int c = k * 16 + cr;
        const f4v* src = reinterpret_cast<const f4v*>(
            &f[((size_t)b * C_ + c) * THW + thw0 + l4 * 4]);
        f4v v = __builtin_nontemporal_load(src);   // f read once; keep L3 for ft
        tile[l4 * 4 + 0][c] = (_Float16)v[0];
        tile[l4 * 4 + 1][c] = (_Float16)v[1];
        tile[l4 * 4 + 2][c] = (_Float16)v[2];
        tile[l4 * 4 + 3][c] = (_Float16)v[3];
    }
    __syncthreads();

    int wv = threadIdx.x >> 6;    // wave 0..3
    int ln = threadIdx.x & 63;
    size_t orow = ((size_t)b * THW + thw0) * C_;
#pragma unroll
    for (int i = 0; i < 16; ++i) {
        int t = wv * 16 + i;
        h4v v = *reinterpret_cast<const h4v*>(&tile[t][ln * 4]);
        // normal (cached) store: ft should stay L3-resident for the gather
        *reinterpret_cast<h4v*>(&ft[orow + (size_t)t * C_ + ln * 4]) = v;
    }
}

// ---------------- main: one block per (roi, 32-channel group) ----------------
// fp16 ft gather (16B half8 taps, 8 ch/thread), t-plane streaming,
// register-accumulated pool, coalesced f4v flush.
__global__ __launch_bounds__(256) void roi_kernel(const _Float16* __restrict__ ft,
                                                  const float* __restrict__ rois,
                                                  float* __restrict__ out) {
    __shared__ float scratch[NOUT];  // 25088 B; first 2112 floats double as plane buffer
    __shared__ float sroi[7];
    __shared__ int2 s_trow[PT]; __shared__ float2 s_twt[PT];
    __shared__ int2 s_yrow[PH]; __shared__ float2 s_ywt[PH];
    __shared__ int2 s_xoff[PW]; __shared__ float2 s_xwt[PW];

    // natural decode: cg in low 3 bits -> round-robin puts each channel-slice
    // on its own XCD (per-XCD L2 working set = ft/8).
    int bid = blockIdx.x;
    int r = bid >> 3;
    int cg = bid & 7;
    int c0 = cg * CG;

    if (threadIdx.x < 7) sroi[threadIdx.x] = rois[r * 7 + threadIdx.x];
    __syncthreads();

    // axis tables: byte offsets (lo/hi) + validity-folded weights
    if (threadIdx.x < 21) {
        int i = threadIdx.x;
        float start, end, size;
        int j, n, scale;
        if (i < 5) {
            j = i; n = PT;
            start = sroi[5] * TSCALE; end = sroi[6] * TSCALE;
            size = (float)T_; scale = H_ * W_ * C_ * 2;
        } else if (i < 13) {
            j = i - 5; n = PH;
            start = sroi[2] * SSCALE; end = sroi[4] * SSCALE;
            size = (float)H_; scale = W_ * C_ * 2;
        } else {
            j = i - 13; n = PW;
            start = sroi[1] * SSCALE; end = sroi[3] * SSCALE;
            size = (float)W_; scale = C_ * 2;
        }
        float length = fmaxf(end - start + 1.0f, 1.0f);
        float step = length / (float)(n - 1);
        float coord = start + step * (float)j;
        float valid = (coord >= 0.0f && coord < size) ? 1.0f : 0.0f;
        float lo = fminf(fmaxf(floorf(coord), 0.0f), size - 1.0f);
        int lo_i = (int)lo;
        int hi_i = min(lo_i + 1, (int)size - 1);
        float fr = coord - lo;
        int2 offs; offs.x = lo_i * scale; offs.y = hi_i * scale;
        float2 wts; wts.x = (1.0f - fr) * valid; wts.y = fr * valid;
        if (i < 5)       { s_trow[j] = offs; s_twt[j] = wts; }
        else if (i < 13) { s_yrow[j] = offs; s_ywt[j] = wts; }
        else             { s_xoff[j] = offs; s_xwt[j] = wts; }
    }
    __syncthreads();

    int b = (int)sroi[0];
    int c4 = threadIdx.x & 3;     // half8 lane: 4 lanes x 8 ch = 32 channels
    int slot = threadIdx.x >> 2;  // 0..63 sample slot (full 8x8 plane in one pass)
    const char* fb = (const char*)ft
        + ((size_t)b * (T_ * H_ * W_ * C_) + (size_t)(c0 + c4 * 8)) * 2;

    float (*buf)[LROW] = (float(*)[LROW])scratch;  // 32 x 66 = 2112 floats
    int cc = threadIdx.x & 31;
    int hh = threadIdx.x >> 5;    // 0..7; hh==7 idle for pooling

    float racc[OT][OW];           // statically indexed (t-loop fully unrolled)
#pragma unroll
    for (int t = 0; t < OT; ++t)
#pragma unroll
        for (int w = 0; w < OW; ++w) racc[t][w] = 0.0f;

    int y = slot >> 3, x = slot & 7;
    int2 yr = s_yrow[y]; float2 yw = s_ywt[y];
    int2 xo = s_xoff[x]; float2 xw = s_xwt[x];

#pragma unroll
    for (int t = 0; t < PT; ++t) {
        if (t) __syncthreads();   // pool reads of plane t-1 done before overwrite

        // ---- compute plane t: 64 samples x 32 channels (8 ch/thread) ----
        int2 tr = s_trow[t];
        float2 tw = s_twt[t];
        int rA = tr.x + yr.x;
        int rB = tr.x + yr.y;
        int rC = tr.y + yr.x;
        int rD = tr.y + yr.y;
        float wA = tw.x * yw.x, wB = tw.x * yw.y;
        float wC = tw.y * yw.x, wD = tw.y * yw.y;

        f4v accL = {0.f, 0.f, 0.f, 0.f};
        f4v accH = {0.f, 0.f, 0.f, 0.f};
#pragma unroll
        for (int tap = 0; tap < 8; ++tap) {
            int ro = (tap & 1) ? ((tap >> 1) == 0 ? rA : (tap >> 1) == 1 ? rB
                                  : (tap >> 1) == 2 ? rC : rD) + xo.y
                               : ((tap >> 1) == 0 ? rA : (tap >> 1) == 1 ? rB
                                  : (tap >> 1) == 2 ? rC : rD) + xo.x;
            float w = ((tap >> 1) == 0 ? wA : (tap >> 1) == 1 ? wB
                       : (tap >> 1) == 2 ? wC : wD) * ((tap & 1) ? xw.y : xw.x);
            h8v h = *(const h8v*)(fb + ro);
            f4v lo = {(float)h[0], (float)h[1], (float)h[2], (float)h[3]};
            f4v hi = {(float)h[4], (float)h[5], (float)h[6], (float)h[7]};
            accL += w * lo;
            accH += w * hi;
        }
        {
            float* col = &buf[c4 * 8][slot];
            col[0 * LROW] = accL[0];
            col[1 * LROW] = accL[1];
            col[2 * LROW] = accL[2];
            col[3 * LROW] = accL[3];
            col[4 * LROW] = accH[0];
            col[5 * LROW] = accH[1];
            col[6 * LROW] = accH[2];
            col[7 * LROW] = accH[3];
        }
        __syncthreads();

        // ---- accumulate plane t into racc[t] (dt=0) and racc[t-1] (dt=1) ----
        if (hh < 7) {
            const float* p = &buf[cc][hh * 8];
            float p2[8];
#pragma unroll
            for (int x2 = 0; x2 < 4; ++x2) {
                f2v a = *(const f2v*)(p + 2 * x2);
                f2v bq = *(const f2v*)(p + 8 + 2 * x2);
                f2v s = a + bq;           // y-pool (rows hh, hh+1)
                p2[2 * x2] = s[0];
                p2[2 * x2 + 1] = s[1];
            }
#pragma unroll
            for (int w = 0; w < OW; ++w) {
                float pw = p2[w] + p2[w + 1];   // x-pool
                if (t < OT) racc[t][w] += pw;
                if (t > 0) racc[t - 1][w] += pw;
            }
        }
    }
    __syncthreads();  // plane buffer dead; scratch reused for flush

    // ---- stage pooled outputs in (c,t,h,w) order, flush coalesced ----
    if (hh < 7) {
        int base = cc * (OT * OH * OW) + hh * OW;
#pragma unroll
        for (int t = 0; t < OT; ++t)
#pragma unroll
            for (int w = 0; w < OW; ++w)
                scratch[base + t * (OH * OW) + w] = racc[t][w] * 0.125f;
    }
    __syncthreads();

    float* outb = out + ((size_t)r * C_ + c0) * (OT * OH * OW);
    const f4v* s4 = (const f4v*)scratch;
    f4v* o4 = (f4v*)outb;
    for (int k = 0; k < 7; ++k) {
        int idx = k * 256 + threadIdx.x;
        if (idx < NOUT / 4) __builtin_nontemporal_store(s4[idx], &o4[idx]);
    }
}

// ---------------- fallback: direct gather, one thread per output ----------------
__device__ __forceinline__ void axis_sample(float start, float end, float size, int n,
                                            int j, int& lo_i, int& hi_i, float& frac,
                                            float& valid) {
    float length = fmaxf(end - start + 1.0f, 1.0f);
    float step = length / (float)(n - 1);
    float coord = start + step * (float)j;
    valid = (coord >= 0.0f && coord < size) ? 1.0f : 0.0f;
    float lo = fminf(fmaxf(floorf(coord), 0.0f), size - 1.0f);
    frac = coord - lo;
    lo_i = (int)lo;
    hi_i = min(lo_i + 1, (int)size - 1);
}

__global__ void roi_direct(const float* __restrict__ f, const float* __restrict__ rois,
                           float* __restrict__ out, long long total) {
    long long idx = (long long)blockIdx.x * 256 + threadIdx.x;
    if (idx >= total) return;
    int w = (int)(idx % OW);
    long long q = idx / OW;
    int h = (int)(q % OH);
    q /= OH;
    int t = (int)(q % OT);
    q /= OT;
    int c = (int)(q % C_);
    int r = (int)(q / C_);

    float rb = rois[r * 7 + 0];
    float x1 = rois[r * 7 + 1] * SSCALE;
    float y1 = rois[r * 7 + 2] * SSCALE;
    float x2 = rois[r * 7 + 3] * SSCALE;
    float y2 = rois[r * 7 + 4] * SSCALE;
    float t1 = rois[r * 7 + 5] * TSCALE;
    float t2 = rois[r * 7 + 6] * TSCALE;
    int b = (int)rb;
    const float* fc = f + ((size_t)b * C_ + c) * (T_ * H_ * W_);

    float acc = 0.0f;
    for (int dt = 0; dt < 2; ++dt) {
        int tlo, thi; float tf, tv;
        axis_sample(t1, t2, (float)T_, PT, t + dt, tlo, thi, tf, tv);
        for (int dh = 0; dh < 2; ++dh) {
            int ylo, yhi; float yf, yv;
            axis_sample(y1, y2, (float)H_, PH, h + dh, ylo, yhi, yf, yv);
            for (int dw = 0; dw < 2; ++dw) {
                int xlo, xhi; float xf, xv;
                axis_sample(x1, x2, (float)W_, PW, w + dw, xlo, xhi, xf, xv);
                float v000 = fc[(tlo * H_ + ylo) * W_ + xlo];
                float v001 = fc[(tlo * H_ + ylo) * W_ + xhi];
                float v010 = fc[(tlo * H_ + yhi) * W_ + xlo];
                float v011 = fc[(tlo * H_ + yhi) * W_ + xhi];
                float v100 = fc[(thi * H_ + ylo) * W_ + xlo];
                float v101 = fc[(thi * H_ + ylo) * W_ + xhi];
                float v110 = fc[(thi * H_ + yhi) * W_ + xlo];
                float v111 = fc[(thi * H_ + yhi) * W_ + xhi];
                float vx00 = v000 + xf * (v001 - v000);
                float vx01 = v010 + xf * (v011 - v010);
                float vx10 = v100 + xf * (v101 - v100);
                float vx11 = v110 + xf * (v111 - v110);
                float vy0 = vx00 + yf * (vx01 - vx00);
                float vy1 = vx10 + yf * (vx11 - vx10);
                float v = vy0 + tf * (vy1 - vy0);
                acc += v * (tv * yv * xv);
            }
        }
    }
    out[idx] = acc * 0.125f;
}

extern "C" void kernel_launch(void* const* d_in, const int* in_sizes, int n_in,
                              void* d_out, int out_size, void* d_ws, size_t ws_size,
                              hipStream_t stream) {
    const float* feat = (const float*)d_in[0];
    const float* rois = (const float*)d_in[1];
    float* out = (float*)d_out;
    int nroi = in_sizes[1] / 7;
    int B = in_sizes[0] / (C_ * T_ * H_ * W_);
    size_t need = (size_t)B * T_ * H_ * W_ * C_ * sizeof(_Float16);

    if (ws_size >= need) {
        dim3 g1(T_ * H_ * W_ / 64, B);
        transpose_kernel<<<g1, 256, 0, stream>>>(feat, (_Float16*)d_ws);
        roi_kernel<<<dim3(nroi * (C_ / CG)), 256, 0, stream>>>((const _Float16*)d_ws, rois, out);
    } else {
        long long total = (long long)nroi * C_ * OT * OH * OW;
        roi_direct<<<(int)((total + 255) / 256), 256, 0, stream>>>(feat, rois, out, total);
    }
}

// Round 6
// 525.282 us; speedup vs baseline: 1.0948x; 1.0948x over previous
//
#include <hip/hip_runtime.h>

#define C_ 256
#define T_ 16
#define H_ 64
#define W_ 64
#define PT 5
#define PH 8
#define PW 8
#define OT 4
#define OH 7
#define OW 7
#define SSCALE (1.0f/16.0f)
#define TSCALE 1.0f
#define CG 32               /* channels per roi block */
#define LROW 66             /* plane row stride: 8B-aligned, 2-way banks max */
#define NOUT (CG * OT * OH * OW)   /* 6272 outputs per block */

typedef float f4v __attribute__((ext_vector_type(4)));
typedef float f2v __attribute__((ext_vector_type(2)));
typedef _Float16 h2v __attribute__((ext_vector_type(2)));
typedef _Float16 h8v __attribute__((ext_vector_type(8)));

// ---------------- transpose+cvt (B,C,T,H,W) f32 -> (B,T,H,W,C) fp16 ----------------
// Channel-PAIR packed u32 LDS tile [64 thw][128 cpair] with XOR swizzle
// (col ^ (row&30)): write side exactly 2-way banks (free), read side full-row
// b64. Reads: 256B/16-lane coalesced NT. Writes: full 512B ft lines per wave.
__global__ __launch_bounds__(256) void transpose_kernel(const float* __restrict__ f,
                                                        _Float16* __restrict__ ft) {
    __shared__ unsigned tile[64 * 128];   // 32 KB
    const int THW = T_ * H_ * W_;
    int thw0 = blockIdx.x * 64;
    int b = blockIdx.y;
    int q = threadIdx.x & 15;      // thw quad
    int cp0 = threadIdx.x >> 4;    // 0..15

#pragma unroll
    for (int k = 0; k < 8; ++k) {
        int cp = k * 16 + cp0;     // channel pair 0..127
        int c = cp * 2;
        const f4v* s0 = reinterpret_cast<const f4v*>(
            &f[((size_t)b * C_ + c) * THW + thw0 + q * 4]);
        const f4v* s1 = reinterpret_cast<const f4v*>(
            &f[((size_t)b * C_ + c + 1) * THW + thw0 + q * 4]);
        f4v va = __builtin_nontemporal_load(s0);
        f4v vb = __builtin_nontemporal_load(s1);
#pragma unroll
        for (int j = 0; j < 4; ++j) {
            int row = q * 4 + j;
            h2v hp = {(_Float16)va[j], (_Float16)vb[j]};
            tile[row * 128 + (cp ^ (row & 30))] = __builtin_bit_cast(unsigned, hp);
        }
    }
    __syncthreads();

    int wv = threadIdx.x >> 6;     // wave 0..3
    int ln = threadIdx.x & 63;
    size_t orow = ((size_t)b * THW + thw0) * C_;
#pragma unroll
    for (int i = 0; i < 16; ++i) {
        int row = wv * 16 + i;
        int s = row & 30;          // even -> pair-preserving XOR -> b64 read
        uint2 w = *reinterpret_cast<const uint2*>(&tile[row * 128 + ((ln * 2) ^ s)]);
        *reinterpret_cast<uint2*>(&ft[orow + (size_t)row * C_ + ln * 4]) = w;
    }
}

// ---------------- spatial roi sort (Morton order) -> perm ----------------
// One block, bitonic over 2048 padded keys. key = (b, morton(y,x), t) << 11 | idx.
__global__ __launch_bounds__(1024) void sort_rois(const float* __restrict__ rois,
                                                  int nroi, int* __restrict__ perm) {
    __shared__ unsigned key[2048];
    int t = threadIdx.x;
    if (nroi > 2048) {             // fallback: identity order
        for (int i = t; i < nroi; i += 1024) perm[i] = i;
        return;
    }
    for (int i = t; i < 2048; i += 1024) {
        unsigned k = 0x1FFFFFu;    // pad key sorts to end
        if (i < nroi) {
            const float* rp = rois + i * 7;
            int bb = (int)rp[0];
            float xc = (rp[1] + rp[3]) * 0.5f * SSCALE;
            float yc = (rp[2] + rp[4]) * 0.5f * SSCALE;
            float tc = (rp[5] + rp[6]) * 0.5f * TSCALE;
            int xq = min(63, max(0, (int)xc));
            int yq = min(63, max(0, (int)yc));
            int tq = min(15, max(0, (int)tc));
            unsigned m = 0;
#pragma unroll
            for (int bit = 0; bit < 6; ++bit)
                m |= (((yq >> bit) & 1u) << (2 * bit + 1)) |
                     (((xq >> bit) & 1u) << (2 * bit));
            k = ((((unsigned)bb << 12) | m) << 4) | (unsigned)tq;   // 18 bits
        }
        key[i] = (k << 11) | (unsigned)i;
    }
    __syncthreads();
    for (int kk = 2; kk <= 2048; kk <<= 1) {
        for (int j = kk >> 1; j > 0; j >>= 1) {
            for (int i = t; i < 2048; i += 1024) {
                int ixj = i ^ j;
                if (ixj > i) {
                    unsigned a = key[i], c = key[ixj];
                    bool up = (i & kk) == 0;
                    if ((a > c) == up) { key[i] = c; key[ixj] = a; }
                }
            }
            __syncthreads();
        }
    }
    for (int i = t; i < 2048; i += 1024)
        if (i < nroi) perm[i] = (int)(key[i] & 0x7FFu);
}

// ---------------- main: one block per (sorted roi, 32-channel group) ----------------
// fp16 ft gather (16B half8 taps, 8 ch/thread), t-plane streaming,
// register-accumulated pool, coalesced f4v flush.
__global__ __launch_bounds__(256) void roi_kernel(const _Float16* __restrict__ ft,
                                                  const float* __restrict__ rois,
                                                  const int* __restrict__ perm,
                                                  float* __restrict__ out) {
    __shared__ float scratch[NOUT];  // 25088 B; first 2112 floats double as plane buffer
    __shared__ float sroi[7];
    __shared__ int2 s_trow[PT]; __shared__ float2 s_twt[PT];
    __shared__ int2 s_yrow[PH]; __shared__ float2 s_ywt[PH];
    __shared__ int2 s_xoff[PW]; __shared__ float2 s_xwt[PW];

    // cg in low 3 bits -> each channel-slice on its own XCD; bid>>3 is the
    // SORTED roi rank, so each XCD walks rois in spatial order (L2 reuse).
    int bid = blockIdx.x;
    int r = perm[bid >> 3];
    int cg = bid & 7;
    int c0 = cg * CG;

    if (threadIdx.x < 7) sroi[threadIdx.x] = rois[r * 7 + threadIdx.x];
    __syncthreads();

    // axis tables: byte offsets (lo/hi) + validity-folded weights
    if (threadIdx.x < 21) {
        int i = threadIdx.x;
        float start, end, size;
        int j, n, scale;
        if (i < 5) {
            j = i; n = PT;
            start = sroi[5] * TSCALE; end = sroi[6] * TSCALE;
            size = (float)T_; scale = H_ * W_ * C_ * 2;
        } else if (i < 13) {
            j = i - 5; n = PH;
            start = sroi[2] * SSCALE; end = sroi[4] * SSCALE;
            size = (float)H_; scale = W_ * C_ * 2;
        } else {
            j = i - 13; n = PW;
            start = sroi[1] * SSCALE; end = sroi[3] * SSCALE;
            size = (float)W_; scale = C_ * 2;
        }
        float length = fmaxf(end - start + 1.0f, 1.0f);
        float step = length / (float)(n - 1);
        float coord = start + step * (float)j;
        float valid = (coord >= 0.0f && coord < size) ? 1.0f : 0.0f;
        float lo = fminf(fmaxf(floorf(coord), 0.0f), size - 1.0f);
        int lo_i = (int)lo;
        int hi_i = min(lo_i + 1, (int)size - 1);
        float fr = coord - lo;
        int2 offs; offs.x = lo_i * scale; offs.y = hi_i * scale;
        float2 wts; wts.x = (1.0f - fr) * valid; wts.y = fr * valid;
        if (i < 5)       { s_trow[j] = offs; s_twt[j] = wts; }
        else if (i < 13) { s_yrow[j] = offs; s_ywt[j] = wts; }
        else             { s_xoff[j] = offs; s_xwt[j] = wts; }
    }
    __syncthreads();

    int b = (int)sroi[0];
    int c4 = threadIdx.x & 3;     // half8 lane: 4 lanes x 8 ch = 32 channels
    int slot = threadIdx.x >> 2;  // 0..63 sample slot (full 8x8 plane in one pass)
    const char* fb = (const char*)ft
        + ((size_t)b * (T_ * H_ * W_ * C_) + (size_t)(c0 + c4 * 8)) * 2;

    float (*buf)[LROW] = (float(*)[LROW])scratch;  // 32 x 66 = 2112 floats
    int cc = threadIdx.x & 31;
    int hh = threadIdx.x >> 5;    // 0..7; hh==7 idle for pooling

    float racc[OT][OW];           // statically indexed (t-loop fully unrolled)
#pragma unroll
    for (int t = 0; t < OT; ++t)
#pragma unroll
        for (int w = 0; w < OW; ++w) racc[t][w] = 0.0f;

    int y = slot >> 3, x = slot & 7;
    int2 yr = s_yrow[y]; float2 yw = s_ywt[y];
    int2 xo = s_xoff[x]; float2 xw = s_xwt[x];

#pragma unroll
    for (int t = 0; t < PT; ++t) {
        if (t) __syncthreads();   // pool reads of plane t-1 done before overwrite

        // ---- compute plane t: 64 samples x 32 channels (8 ch/thread) ----
        int2 tr = s_trow[t];
        float2 tw = s_twt[t];
        int rA = tr.x + yr.x;
        int rB = tr.x + yr.y;
        int rC = tr.y + yr.x;
        int rD = tr.y + yr.y;
        float wA = tw.x * yw.x, wB = tw.x * yw.y;
        float wC = tw.y * yw.x, wD = tw.y * yw.y;

        f4v accL = {0.f, 0.f, 0.f, 0.f};
        f4v accH = {0.f, 0.f, 0.f, 0.f};
#pragma unroll
        for (int tap = 0; tap < 8; ++tap) {
            int ro = (tap & 1) ? ((tap >> 1) == 0 ? rA : (tap >> 1) == 1 ? rB
                                  : (tap >> 1) == 2 ? rC : rD) + xo.y
                               : ((tap >> 1) == 0 ? rA : (tap >> 1) == 1 ? rB
                                  : (tap >> 1) == 2 ? rC : rD) + xo.x;
            float w = ((tap >> 1) == 0 ? wA : (tap >> 1) == 1 ? wB
                       : (tap >> 1) == 2 ? wC : wD) * ((tap & 1) ? xw.y : xw.x);
            h8v h = *(const h8v*)(fb + ro);
            f4v lo = {(float)h[0], (float)h[1], (float)h[2], (float)h[3]};
            f4v hi = {(float)h[4], (float)h[5], (float)h[6], (float)h[7]};
            accL += w * lo;
            accH += w * hi;
        }
        {
            float* col = &buf[c4 * 8][slot];
            col[0 * LROW] = accL[0];
            col[1 * LROW] = accL[1];
            col[2 * LROW] = accL[2];
            col[3 * LROW] = accL[3];
            col[4 * LROW] = accH[0];
            col[5 * LROW] = accH[1];
            col[6 * LROW] = accH[2];
            col[7 * LROW] = accH[3];
        }
        __syncthreads();

        // ---- accumulate plane t into racc[t] (dt=0) and racc[t-1] (dt=1) ----
        if (hh < 7) {
            const float* p = &buf[cc][hh * 8];
            float p2[8];
#pragma unroll
            for (int x2 = 0; x2 < 4; ++x2) {
                f2v a = *(const f2v*)(p + 2 * x2);
                f2v bq = *(const f2v*)(p + 8 + 2 * x2);
                f2v s = a + bq;           // y-pool (rows hh, hh+1)
                p2[2 * x2] = s[0];
                p2[2 * x2 + 1] = s[1];
            }
#pragma unroll
            for (int w = 0; w < OW; ++w) {
                float pw = p2[w] + p2[w + 1];   // x-pool
                if (t < OT) racc[t][w] += pw;
                if (t > 0) racc[t - 1][w] += pw;
            }
        }
    }
    __syncthreads();  // plane buffer dead; scratch reused for flush

    // ---- stage pooled outputs in (c,t,h,w) order, flush coalesced ----
    if (hh < 7) {
        int base = cc * (OT * OH * OW) + hh * OW;
#pragma unroll
        for (int t = 0; t < OT; ++t)
#pragma unroll
            for (int w = 0; w < OW; ++w)
                scratch[base + t * (OH * OW) + w] = racc[t][w] * 0.125f;
    }
    __syncthreads();

    float* outb = out + ((size_t)r * C_ + c0) * (OT * OH * OW);
    const f4v* s4 = (const f4v*)scratch;
    f4v* o4 = (f4v*)outb;
    for (int k = 0; k < 7; ++k) {
        int idx = k * 256 + threadIdx.x;
        if (idx < NOUT / 4) __builtin_nontemporal_store(s4[idx], &o4[idx]);
    }
}

// ---------------- fallback: direct gather, one thread per output ----------------
__device__ __forceinline__ void axis_sample(float start, float end, float size, int n,
                                            int j, int& lo_i, int& hi_i, float& frac,
                                            float& valid) {
    float length = fmaxf(end - start + 1.0f, 1.0f);
    float step = length / (float)(n - 1);
    float coord = start + step * (float)j;
    valid = (coord >= 0.0f && coord < size) ? 1.0f : 0.0f;
    float lo = fminf(fmaxf(floorf(coord), 0.0f), size - 1.0f);
    frac = coord - lo;
    lo_i = (int)lo;
    hi_i = min(lo_i + 1, (int)size - 1);
}

__global__ void roi_direct(const float* __restrict__ f, const float* __restrict__ rois,
                           float* __restrict__ out, long long total) {
    long long idx = (long long)blockIdx.x * 256 + threadIdx.x;
    if (idx >= total) return;
    int w = (int)(idx % OW);
    long long q = idx / OW;
    int h = (int)(q % OH);
    q /= OH;
    int t = (int)(q % OT);
    q /= OT;
    int c = (int)(q % C_);
    int r = (int)(q / C_);

    float rb = rois[r * 7 + 0];
    float x1 = rois[r * 7 + 1] * SSCALE;
    float y1 = rois[r * 7 + 2] * SSCALE;
    float x2 = rois[r * 7 + 3] * SSCALE;
    float y2 = rois[r * 7 + 4] * SSCALE;
    float t1 = rois[r * 7 + 5] * TSCALE;
    float t2 = rois[r * 7 + 6] * TSCALE;
    int b = (int)rb;
    const float* fc = f + ((size_t)b * C_ + c) * (T_ * H_ * W_);

    float acc = 0.0f;
    for (int dt = 0; dt < 2; ++dt) {
        int tlo, thi; float tf, tv;
        axis_sample(t1, t2, (float)T_, PT, t + dt, tlo, thi, tf, tv);
        for (int dh = 0; dh < 2; ++dh) {
            int ylo, yhi; float yf, yv;
            axis_sample(y1, y2, (float)H_, PH, h + dh, ylo, yhi, yf, yv);
            for (int dw = 0; dw < 2; ++dw) {
                int xlo, xhi; float xf, xv;
                axis_sample(x1, x2, (float)W_, PW, w + dw, xlo, xhi, xf, xv);
                float v000 = fc[(tlo * H_ + ylo) * W_ + xlo];
                float v001 = fc[(tlo * H_ + ylo) * W_ + xhi];
                float v010 = fc[(tlo * H_ + yhi) * W_ + xlo];
                float v011 = fc[(tlo * H_ + yhi) * W_ + xhi];
                float v100 = fc[(thi * H_ + ylo) * W_ + xlo];
                float v101 = fc[(thi * H_ + ylo) * W_ + xhi];
                float v110 = fc[(thi * H_ + yhi) * W_ + xlo];
                float v111 = fc[(thi * H_ + yhi) * W_ + xhi];
                float vx00 = v000 + xf * (v001 - v000);
                float vx01 = v010 + xf * (v011 - v010);
                float vx10 = v100 + xf * (v101 - v100);
                float vx11 = v110 + xf * (v111 - v110);
                float vy0 = vx00 + yf * (vx01 - vx00);
                float vy1 = vx10 + yf * (vx11 - vx10);
                float v = vy0 + tf * (vy1 - vy0);
                acc += v * (tv * yv * xv);
            }
        }
    }
    out[idx] = acc * 0.125f;
}

extern "C" void kernel_launch(void* const* d_in, const int* in_sizes, int n_in,
                              void* d_out, int out_size, void* d_ws, size_t ws_size,
                              hipStream_t stream) {
    const float* feat = (const float*)d_in[0];
    const float* rois = (const float*)d_in[1];
    float* out = (float*)d_out;
    int nroi = in_sizes[1] / 7;
    int B = in_sizes[0] / (C_ * T_ * H_ * W_);
    size_t ftbytes = (size_t)B * T_ * H_ * W_ * C_ * sizeof(_Float16);
    size_t need = ftbytes + 2048 * sizeof(int);

    if (ws_size >= need && nroi >= 1) {
        _Float16* ft = (_Float16*)d_ws;
        int* perm = (int*)((char*)d_ws + ftbytes);
        sort_rois<<<1, 1024, 0, stream>>>(rois, nroi, perm);
        dim3 g1(T_ * H_ * W_ / 64, B);
        transpose_kernel<<<g1, 256, 0, stream>>>(feat, ft);
        roi_kernel<<<dim3(nroi * (C_ / CG)), 256, 0, stream>>>(ft, rois, perm, out);
    } else {
        long long total = (long long)nroi * C_ * OT * OH * OW;
        roi_direct<<<(int)((total + 255) / 256), 256, 0, stream>>>(feat, rois, out, total);
    }
}

// Round 7
// 524.188 us; speedup vs baseline: 1.0971x; 1.0021x over previous
//
#include <hip/hip_runtime.h>

#define C_ 256
#define T_ 16
#define H_ 64
#define W_ 64
#define PT 5
#define PH 8
#define PW 8
#define OT 4
#define OH 7
#define OW 7
#define SSCALE (1.0f/16.0f)
#define TSCALE 1.0f
#define CG 32               /* channels per roi block */
#define LROW 66             /* plane row stride: 8B-aligned, 2-way banks max */
#define PLN (CG * LROW)     /* 2112 floats per plane buffer */
#define NOUT (CG * OT * OH * OW)   /* 6272 outputs per block */

typedef float f4v __attribute__((ext_vector_type(4)));
typedef float f2v __attribute__((ext_vector_type(2)));
typedef _Float16 h2v __attribute__((ext_vector_type(2)));
typedef _Float16 h8v __attribute__((ext_vector_type(8)));

__device__ __forceinline__ f4v lo4(h8v h) {
    f4v r = {(float)h[0], (float)h[1], (float)h[2], (float)h[3]};
    return r;
}
__device__ __forceinline__ f4v hi4(h8v h) {
    f4v r = {(float)h[4], (float)h[5], (float)h[6], (float)h[7]};
    return r;
}

// ---------------- transpose+cvt (B,C,T,H,W) f32 -> (B,T,H,W,C) fp16 ----------------
// Channel-PAIR packed u32 LDS tile [64 thw][128 cpair] with XOR swizzle
// (col ^ (row&30)): write side exactly 2-way banks (free), read side full-row
// b64. Reads: 256B/16-lane coalesced NT. Writes: full 512B ft lines per wave.
__global__ __launch_bounds__(256) void transpose_kernel(const float* __restrict__ f,
                                                        _Float16* __restrict__ ft) {
    __shared__ unsigned tile[64 * 128];   // 32 KB
    const int THW = T_ * H_ * W_;
    int thw0 = blockIdx.x * 64;
    int b = blockIdx.y;
    int q = threadIdx.x & 15;      // thw quad
    int cp0 = threadIdx.x >> 4;    // 0..15

#pragma unroll
    for (int k = 0; k < 8; ++k) {
        int cp = k * 16 + cp0;     // channel pair 0..127
        int c = cp * 2;
        const f4v* s0 = reinterpret_cast<const f4v*>(
            &f[((size_t)b * C_ + c) * THW + thw0 + q * 4]);
        const f4v* s1 = reinterpret_cast<const f4v*>(
            &f[((size_t)b * C_ + c + 1) * THW + thw0 + q * 4]);
        f4v va = __builtin_nontemporal_load(s0);
        f4v vb = __builtin_nontemporal_load(s1);
#pragma unroll
        for (int j = 0; j < 4; ++j) {
            int row = q * 4 + j;
            h2v hp = {(_Float16)va[j], (_Float16)vb[j]};
            tile[row * 128 + (cp ^ (row & 30))] = __builtin_bit_cast(unsigned, hp);
        }
    }
    __syncthreads();

    int wv = threadIdx.x >> 6;     // wave 0..3
    int ln = threadIdx.x & 63;
    size_t orow = ((size_t)b * THW + thw0) * C_;
#pragma unroll
    for (int i = 0; i < 16; ++i) {
        int row = wv * 16 + i;
        int s = row & 30;          // even -> pair-preserving XOR -> b64 read
        uint2 w = *reinterpret_cast<const uint2*>(&tile[row * 128 + ((ln * 2) ^ s)]);
        *reinterpret_cast<uint2*>(&ft[orow + (size_t)row * C_ + ln * 4]) = w;
    }
}

// ---------------- spatial roi sort (Morton order) -> perm ----------------
// One block, bitonic over 2048 padded keys. key = (b, morton(y,x), t) << 11 | idx.
__global__ __launch_bounds__(1024) void sort_rois(const float* __restrict__ rois,
                                                  int nroi, int* __restrict__ perm) {
    __shared__ unsigned key[2048];
    int t = threadIdx.x;
    if (nroi > 2048) {             // fallback: identity order
        for (int i = t; i < nroi; i += 1024) perm[i] = i;
        return;
    }
    for (int i = t; i < 2048; i += 1024) {
        unsigned k = 0x1FFFFFu;    // pad key sorts to end
        if (i < nroi) {
            const float* rp = rois + i * 7;
            int bb = (int)rp[0];
            float xc = (rp[1] + rp[3]) * 0.5f * SSCALE;
            float yc = (rp[2] + rp[4]) * 0.5f * SSCALE;
            float tc = (rp[5] + rp[6]) * 0.5f * TSCALE;
            int xq = min(63, max(0, (int)xc));
            int yq = min(63, max(0, (int)yc));
            int tq = min(15, max(0, (int)tc));
            unsigned m = 0;
#pragma unroll
            for (int bit = 0; bit < 6; ++bit)
                m |= (((yq >> bit) & 1u) << (2 * bit + 1)) |
                     (((xq >> bit) & 1u) << (2 * bit));
            k = ((((unsigned)bb << 12) | m) << 4) | (unsigned)tq;   // 18 bits
        }
        key[i] = (k << 11) | (unsigned)i;
    }
    __syncthreads();
    for (int kk = 2; kk <= 2048; kk <<= 1) {
        for (int j = kk >> 1; j > 0; j >>= 1) {
            for (int i = t; i < 2048; i += 1024) {
                int ixj = i ^ j;
                if (ixj > i) {
                    unsigned a = key[i], c = key[ixj];
                    bool up = (i & kk) == 0;
                    if ((a > c) == up) { key[i] = c; key[ixj] = a; }
                }
            }
            __syncthreads();
        }
    }
    for (int i = t; i < 2048; i += 1024)
        if (i < nroi) perm[i] = (int)(key[i] & 0x7FFu);
}

// ---------------- main: one block per (sorted roi, 32-channel group) ----------------
// fp16 ft gather (16B half8 taps, 8 ch/thread), t-plane streaming with
// REGISTER PREFETCH of the next plane's 8 taps (latency hidden under
// interp+pool), double-buffered plane (1 barrier/plane), register-
// accumulated pool, coalesced f4v flush.
__global__ __launch_bounds__(256, 4) void roi_kernel(const _Float16* __restrict__ ft,
                                                     const float* __restrict__ rois,
                                                     const int* __restrict__ perm,
                                                     float* __restrict__ out) {
    __shared__ float scratch[NOUT];  // 25088 B; first 2*2112 floats = plane dbuf
    __shared__ float sroi[7];
    __shared__ int2 s_trow[PT]; __shared__ float2 s_twt[PT];
    __shared__ int2 s_yrow[PH]; __shared__ float2 s_ywt[PH];
    __shared__ int2 s_xoff[PW]; __shared__ float2 s_xwt[PW];

    // cg in low 3 bits -> each channel-slice on its own XCD; bid>>3 is the
    // SORTED roi rank, so each XCD walks rois in spatial order (L2 reuse).
    int bid = blockIdx.x;
    int r = perm[bid >> 3];
    int cg = bid & 7;
    int c0 = cg * CG;

    if (threadIdx.x < 7) sroi[threadIdx.x] = rois[r * 7 + threadIdx.x];
    __syncthreads();

    // axis tables: byte offsets (lo/hi) + validity-folded weights
    if (threadIdx.x < 21) {
        int i = threadIdx.x;
        float start, end, size;
        int j, n, scale;
        if (i < 5) {
            j = i; n = PT;
            start = sroi[5] * TSCALE; end = sroi[6] * TSCALE;
            size = (float)T_; scale = H_ * W_ * C_ * 2;
        } else if (i < 13) {
            j = i - 5; n = PH;
            start = sroi[2] * SSCALE; end = sroi[4] * SSCALE;
            size = (float)H_; scale = W_ * C_ * 2;
        } else {
            j = i - 13; n = PW;
            start = sroi[1] * SSCALE; end = sroi[3] * SSCALE;
            size = (float)W_; scale = C_ * 2;
        }
        float length = fmaxf(end - start + 1.0f, 1.0f);
        float step = length / (float)(n - 1);
        float coord = start + step * (float)j;
        float valid = (coord >= 0.0f && coord < size) ? 1.0f : 0.0f;
        float lo = fminf(fmaxf(floorf(coord), 0.0f), size - 1.0f);
        int lo_i = (int)lo;
        int hi_i = min(lo_i + 1, (int)size - 1);
        float fr = coord - lo;
        int2 offs; offs.x = lo_i * scale; offs.y = hi_i * scale;
        float2 wts; wts.x = (1.0f - fr) * valid; wts.y = fr * valid;
        if (i < 5)       { s_trow[j] = offs; s_twt[j] = wts; }
        else if (i < 13) { s_yrow[j] = offs; s_ywt[j] = wts; }
        else             { s_xoff[j] = offs; s_xwt[j] = wts; }
    }
    __syncthreads();

    int b = (int)sroi[0];
    int c4 = threadIdx.x & 3;     // half8 lane: 4 lanes x 8 ch = 32 channels
    int slot = threadIdx.x >> 2;  // 0..63 sample slot (full 8x8 plane in one pass)
    const char* fb = (const char*)ft
        + ((size_t)b * (T_ * H_ * W_ * C_) + (size_t)(c0 + c4 * 8)) * 2;

    float* bufs[2] = {scratch, scratch + PLN};
    int cc = threadIdx.x & 31;
    int hh = threadIdx.x >> 5;    // 0..7; hh==7 idle for pooling

    float racc[OT][OW];           // statically indexed (t-loop fully unrolled)
#pragma unroll
    for (int t = 0; t < OT; ++t)
#pragma unroll
        for (int w = 0; w < OW; ++w) racc[t][w] = 0.0f;

    int y = slot >> 3, x = slot & 7;
    int2 yr = s_yrow[y]; float2 yw = s_ywt[y];
    int2 xo = s_xoff[x]; float2 xw = s_xwt[x];
    int o00 = yr.x + xo.x, o01 = yr.x + xo.y;
    int o10 = yr.y + xo.x, o11 = yr.y + xo.y;

    h8v cur[8], nxt[8];
    {   // prologue: plane 0 taps
        int2 tr = s_trow[0];
        cur[0] = *(const h8v*)(fb + tr.x + o00);
        cur[1] = *(const h8v*)(fb + tr.x + o01);
        cur[2] = *(const h8v*)(fb + tr.x + o10);
        cur[3] = *(const h8v*)(fb + tr.x + o11);
        cur[4] = *(const h8v*)(fb + tr.y + o00);
        cur[5] = *(const h8v*)(fb + tr.y + o01);
        cur[6] = *(const h8v*)(fb + tr.y + o10);
        cur[7] = *(const h8v*)(fb + tr.y + o11);
    }

#pragma unroll
    for (int t = 0; t < PT; ++t) {
        // ---- issue next plane's taps FIRST (latency hides under interp+pool) ----
        if (t + 1 < PT) {
            int2 tr = s_trow[t + 1];
            nxt[0] = *(const h8v*)(fb + tr.x + o00);
            nxt[1] = *(const h8v*)(fb + tr.x + o01);
            nxt[2] = *(const h8v*)(fb + tr.x + o10);
            nxt[3] = *(const h8v*)(fb + tr.x + o11);
            nxt[4] = *(const h8v*)(fb + tr.y + o00);
            nxt[5] = *(const h8v*)(fb + tr.y + o01);
            nxt[6] = *(const h8v*)(fb + tr.y + o10);
            nxt[7] = *(const h8v*)(fb + tr.y + o11);
        }

        // ---- interpolate plane t from cur, write to buf[t&1] ----
        float2 tw = s_twt[t];
        f4v vx00L = xw.x * lo4(cur[0]) + xw.y * lo4(cur[1]);
        f4v vx01L = xw.x * lo4(cur[2]) + xw.y * lo4(cur[3]);
        f4v vx10L = xw.x * lo4(cur[4]) + xw.y * lo4(cur[5]);
        f4v vx11L = xw.x * lo4(cur[6]) + xw.y * lo4(cur[7]);
        f4v vx00H = xw.x * hi4(cur[0]) + xw.y * hi4(cur[1]);
        f4v vx01H = xw.x * hi4(cur[2]) + xw.y * hi4(cur[3]);
        f4v vx10H = xw.x * hi4(cur[4]) + xw.y * hi4(cur[5]);
        f4v vx11H = xw.x * hi4(cur[6]) + xw.y * hi4(cur[7]);
        f4v vL = tw.x * (yw.x * vx00L + yw.y * vx01L)
               + tw.y * (yw.x * vx10L + yw.y * vx11L);
        f4v vH = tw.x * (yw.x * vx00H + yw.y * vx01H)
               + tw.y * (yw.x * vx10H + yw.y * vx11H);

        float* bp = bufs[t & 1];
        {
            float* col = &bp[(c4 * 8) * LROW + slot];
            col[0 * LROW] = vL[0];
            col[1 * LROW] = vL[1];
            col[2 * LROW] = vL[2];
            col[3 * LROW] = vL[3];
            col[4 * LROW] = vH[0];
            col[5 * LROW] = vH[1];
            col[6 * LROW] = vH[2];
            col[7 * LROW] = vH[3];
        }
        __syncthreads();   // single barrier/plane: next write hits other buffer

        // ---- accumulate plane t into racc[t] (dt=0) and racc[t-1] (dt=1) ----
        if (hh < 7) {
            const float* p = &bp[cc * LROW + hh * 8];
            float p2[8];
#pragma unroll
            for (int x2 = 0; x2 < 4; ++x2) {
                f2v a = *(const f2v*)(p + 2 * x2);
                f2v bq = *(const f2v*)(p + 8 + 2 * x2);
                f2v s = a + bq;           // y-pool (rows hh, hh+1)
                p2[2 * x2] = s[0];
                p2[2 * x2 + 1] = s[1];
            }
#pragma unroll
            for (int w = 0; w < OW; ++w) {
                float pw = p2[w] + p2[w + 1];   // x-pool
                if (t < OT) racc[t][w] += pw;
                if (t > 0) racc[t - 1][w] += pw;
            }
        }

#pragma unroll
        for (int i = 0; i < 8; ++i) cur[i] = nxt[i];
    }
    __syncthreads();  // plane dbuf dead; scratch reused for flush

    // ---- stage pooled outputs in (c,t,h,w) order, flush coalesced ----
    if (hh < 7) {
        int base = cc * (OT * OH * OW) + hh * OW;
#pragma unroll
        for (int t = 0; t < OT; ++t)
#pragma unroll
            for (int w = 0; w < OW; ++w)
                scratch[base + t * (OH * OW) + w] = racc[t][w] * 0.125f;
    }
    __syncthreads();

    float* outb = out + ((size_t)r * C_ + c0) * (OT * OH * OW);
    const f4v* s4 = (const f4v*)scratch;
    f4v* o4 = (f4v*)outb;
    for (int k = 0; k < 7; ++k) {
        int idx = k * 256 + threadIdx.x;
        if (idx < NOUT / 4) __builtin_nontemporal_store(s4[idx], &o4[idx]);
    }
}

// ---------------- fallback: direct gather, one thread per output ----------------
__device__ __forceinline__ void axis_sample(float start, float end, float size, int n,
                                            int j, int& lo_i, int& hi_i, float& frac,
                                            float& valid) {
    float length = fmaxf(end - start + 1.0f, 1.0f);
    float step = length / (float)(n - 1);
    float coord = start + step * (float)j;
    valid = (coord >= 0.0f && coord < size) ? 1.0f : 0.0f;
    float lo = fminf(fmaxf(floorf(coord), 0.0f), size - 1.0f);
    frac = coord - lo;
    lo_i = (int)lo;
    hi_i = min(lo_i + 1, (int)size - 1);
}

__global__ void roi_direct(const float* __restrict__ f, const float* __restrict__ rois,
                           float* __restrict__ out, long long total) {
    long long idx = (long long)blockIdx.x * 256 + threadIdx.x;
    if (idx >= total) return;
    int w = (int)(idx % OW);
    long long q = idx / OW;
    int h = (int)(q % OH);
    q /= OH;
    int t = (int)(q % OT);
    q /= OT;
    int c = (int)(q % C_);
    int r = (int)(q / C_);

    float rb = rois[r * 7 + 0];
    float x1 = rois[r * 7 + 1] * SSCALE;
    float y1 = rois[r * 7 + 2] * SSCALE;
    float x2 = rois[r * 7 + 3] * SSCALE;
    float y2 = rois[r * 7 + 4] * SSCALE;
    float t1 = rois[r * 7 + 5] * TSCALE;
    float t2 = rois[r * 7 + 6] * TSCALE;
    int b = (int)rb;
    const float* fc = f + ((size_t)b * C_ + c) * (T_ * H_ * W_);

    float acc = 0.0f;
    for (int dt = 0; dt < 2; ++dt) {
        int tlo, thi; float tf, tv;
        axis_sample(t1, t2, (float)T_, PT, t + dt, tlo, thi, tf, tv);
        for (int dh = 0; dh < 2; ++dh) {
            int ylo, yhi; float yf, yv;
            axis_sample(y1, y2, (float)H_, PH, h + dh, ylo, yhi, yf, yv);
            for (int dw = 0; dw < 2; ++dw) {
                int xlo, xhi; float xf, xv;
                axis_sample(x1, x2, (float)W_, PW, w + dw, xlo, xhi, xf, xv);
                float v000 = fc[(tlo * H_ + ylo) * W_ + xlo];
                float v001 = fc[(tlo * H_ + ylo) * W_ + xhi];
                float v010 = fc[(tlo * H_ + yhi) * W_ + xlo];
                float v011 = fc[(tlo * H_ + yhi) * W_ + xhi];
                float v100 = fc[(thi * H_ + ylo) * W_ + xlo];
                float v101 = fc[(thi * H_ + ylo) * W_ + xhi];
                float v110 = fc[(thi * H_ + yhi) * W_ + xlo];
                float v111 = fc[(thi * H_ + yhi) * W_ + xhi];
                float vx00 = v000 + xf * (v001 - v000);
                float vx01 = v010 + xf * (v011 - v010);
                float vx10 = v100 + xf * (v101 - v100);
                float vx11 = v110 + xf * (v111 - v110);
                float vy0 = vx00 + yf * (vx01 - vx00);
                float vy1 = vx10 + yf * (vx11 - vx10);
                float v = vy0 + tf * (vy1 - vy0);
                acc += v * (tv * yv * xv);
            }
        }
    }
    out[idx] = acc * 0.125f;
}

extern "C" void kernel_launch(void* const* d_in, const int* in_sizes, int n_in,
                              void* d_out, int out_size, void* d_ws, size_t ws_size,
                              hipStream_t stream) {
    const float* feat = (const float*)d_in[0];
    const float* rois = (const float*)d_in[1];
    float* out = (float*)d_out;
    int nroi = in_sizes[1] / 7;
    int B = in_sizes[0] / (C_ * T_ * H_ * W_);
    size_t ftbytes = (size_t)B * T_ * H_ * W_ * C_ * sizeof(_Float16);
    size_t need = ftbytes + 2048 * sizeof(int);

    if (ws_size >= need && nroi >= 1) {
        _Float16* ft = (_Float16*)d_ws;
        int* perm = (int*)((char*)d_ws + ftbytes);
        sort_rois<<<1, 1024, 0, stream>>>(rois, nroi, perm);
        dim3 g1(T_ * H_ * W_ / 64, B);
        transpose_kernel<<<g1, 256, 0, stream>>>(feat, ft);
        roi_kernel<<<dim3(nroi * (C_ / CG)), 256, 0, stream>>>(ft, rois, perm, out);
    } else {
        long long total = (long long)nroi * C_ * OT * OH * OW;
        roi_direct<<<(int)((total + 255) / 256), 256, 0, stream>>>(feat, rois, out, total);
    }
}

// Round 8
// 524.157 us; speedup vs baseline: 1.0972x; 1.0001x over previous
//
#include <hip/hip_runtime.h>

#define C_ 256
#define T_ 16
#define H_ 64
#define W_ 64
#define PT 5
#define PH 8
#define PW 8
#define OT 4
#define OH 7
#define OW 7
#define SSCALE (1.0f/16.0f)
#define TSCALE 1.0f
#define CG 64               /* channels per roi block: 64ch = one full 128B L2 line slice */
#define LROW 66             /* plane col stride: 8B-aligned f2v pool reads, <=4-way banks */
#define PLN (CG * LROW)     /* 4224 floats per plane buffer */
#define NOUT (CG * OT * OH * OW)   /* 12544 outputs per block */

typedef float f4v __attribute__((ext_vector_type(4)));
typedef float f2v __attribute__((ext_vector_type(2)));
typedef _Float16 h2v __attribute__((ext_vector_type(2)));
typedef _Float16 h8v __attribute__((ext_vector_type(8)));

__device__ __forceinline__ f4v lo4(h8v h) {
    f4v r = {(float)h[0], (float)h[1], (float)h[2], (float)h[3]};
    return r;
}
__device__ __forceinline__ f4v hi4(h8v h) {
    f4v r = {(float)h[4], (float)h[5], (float)h[6], (float)h[7]};
    return r;
}

// ---------------- transpose+cvt (B,C,T,H,W) f32 -> (B,T,H,W,C) fp16 ----------------
// Channel-PAIR packed u32 LDS tile [64 thw][128 cpair] with XOR swizzle
// (col ^ (row&30)): write side exactly 2-way banks (free), read side full-row
// b64. Reads: 256B/16-lane coalesced NT. Writes: full 512B ft lines per wave.
__global__ __launch_bounds__(256) void transpose_kernel(const float* __restrict__ f,
                                                        _Float16* __restrict__ ft) {
    __shared__ unsigned tile[64 * 128];   // 32 KB
    const int THW = T_ * H_ * W_;
    int thw0 = blockIdx.x * 64;
    int b = blockIdx.y;
    int q = threadIdx.x & 15;      // thw quad
    int cp0 = threadIdx.x >> 4;    // 0..15

#pragma unroll
    for (int k = 0; k < 8; ++k) {
        int cp = k * 16 + cp0;     // channel pair 0..127
        int c = cp * 2;
        const f4v* s0 = reinterpret_cast<const f4v*>(
            &f[((size_t)b * C_ + c) * THW + thw0 + q * 4]);
        const f4v* s1 = reinterpret_cast<const f4v*>(
            &f[((size_t)b * C_ + c + 1) * THW + thw0 + q * 4]);
        f4v va = __builtin_nontemporal_load(s0);
        f4v vb = __builtin_nontemporal_load(s1);
#pragma unroll
        for (int j = 0; j < 4; ++j) {
            int row = q * 4 + j;
            h2v hp = {(_Float16)va[j], (_Float16)vb[j]};
            tile[row * 128 + (cp ^ (row & 30))] = __builtin_bit_cast(unsigned, hp);
        }
    }
    __syncthreads();

    int wv = threadIdx.x >> 6;     // wave 0..3
    int ln = threadIdx.x & 63;
    size_t orow = ((size_t)b * THW + thw0) * C_;
#pragma unroll
    for (int i = 0; i < 16; ++i) {
        int row = wv * 16 + i;
        int s = row & 30;          // even -> pair-preserving XOR -> b64 read
        uint2 w = *reinterpret_cast<const uint2*>(&tile[row * 128 + ((ln * 2) ^ s)]);
        *reinterpret_cast<uint2*>(&ft[orow + (size_t)row * C_ + ln * 4]) = w;
    }
}

// ---------------- spatial roi sort (Morton order) -> perm ----------------
// One block, bitonic over 2048 padded keys. key = (b, morton(y,x), t) << 11 | idx.
__global__ __launch_bounds__(1024) void sort_rois(const float* __restrict__ rois,
                                                  int nroi, int* __restrict__ perm) {
    __shared__ unsigned key[2048];
    int t = threadIdx.x;
    if (nroi > 2048) {             // fallback: identity order
        for (int i = t; i < nroi; i += 1024) perm[i] = i;
        return;
    }
    for (int i = t; i < 2048; i += 1024) {
        unsigned k = 0x1FFFFFu;    // pad key sorts to end
        if (i < nroi) {
            const float* rp = rois + i * 7;
            int bb = (int)rp[0];
            float xc = (rp[1] + rp[3]) * 0.5f * SSCALE;
            float yc = (rp[2] + rp[4]) * 0.5f * SSCALE;
            float tc = (rp[5] + rp[6]) * 0.5f * TSCALE;
            int xq = min(63, max(0, (int)xc));
            int yq = min(63, max(0, (int)yc));
            int tq = min(15, max(0, (int)tc));
            unsigned m = 0;
#pragma unroll
            for (int bit = 0; bit < 6; ++bit)
                m |= (((yq >> bit) & 1u) << (2 * bit + 1)) |
                     (((xq >> bit) & 1u) << (2 * bit));
            k = ((((unsigned)bb << 12) | m) << 4) | (unsigned)tq;   // 18 bits
        }
        key[i] = (k << 11) | (unsigned)i;
    }
    __syncthreads();
    for (int kk = 2; kk <= 2048; kk <<= 1) {
        for (int j = kk >> 1; j > 0; j >>= 1) {
            for (int i = t; i < 2048; i += 1024) {
                int ixj = i ^ j;
                if (ixj > i) {
                    unsigned a = key[i], c = key[ixj];
                    bool up = (i & kk) == 0;
                    if ((a > c) == up) { key[i] = c; key[ixj] = a; }
                }
            }
            __syncthreads();
        }
    }
    for (int i = t; i < 2048; i += 1024)
        if (i < nroi) perm[i] = (int)(key[i] & 0x7FFu);
}

// ---------------- main: one 512-thread block per (sorted roi, 64-channel group) ----------------
// Each block's channel slice = one full 128B L2 line per ft row -> no
// cross-XCD line duplication. fp16 half8 taps (8 ch/thread, full 8x8 plane
// in one pass), t-plane streaming, double-buffered plane (1 barrier/plane),
// register-accumulated pool, coalesced f4v flush.
__global__ __launch_bounds__(512) void roi_kernel(const _Float16* __restrict__ ft,
                                                  const float* __restrict__ rois,
                                                  const int* __restrict__ perm,
                                                  float* __restrict__ out) {
    __shared__ float scratch[NOUT];  // 50176 B; first 2*4224 floats = plane dbuf
    __shared__ float sroi[7];
    __shared__ int2 s_trow[PT]; __shared__ float2 s_twt[PT];
    __shared__ int2 s_yrow[PH]; __shared__ float2 s_ywt[PH];
    __shared__ int2 s_xoff[PW]; __shared__ float2 s_xwt[PW];

    // cg in low 2 bits; bid>>2 is the SORTED roi rank: XCDs walk rois in
    // spatial order (L2 reuse), each cg slice owns whole 128B lines.
    int bid = blockIdx.x;
    int r = perm[bid >> 2];
    int cg = bid & 3;
    int c0 = cg * CG;

    if (threadIdx.x < 7) sroi[threadIdx.x] = rois[r * 7 + threadIdx.x];
    __syncthreads();

    // axis tables: byte offsets (lo/hi) + validity-folded weights
    if (threadIdx.x < 21) {
        int i = threadIdx.x;
        float start, end, size;
        int j, n, scale;
        if (i < 5) {
            j = i; n = PT;
            start = sroi[5] * TSCALE; end = sroi[6] * TSCALE;
            size = (float)T_; scale = H_ * W_ * C_ * 2;
        } else if (i < 13) {
            j = i - 5; n = PH;
            start = sroi[2] * SSCALE; end = sroi[4] * SSCALE;
            size = (float)H_; scale = W_ * C_ * 2;
        } else {
            j = i - 13; n = PW;
            start = sroi[1] * SSCALE; end = sroi[3] * SSCALE;
            size = (float)W_; scale = C_ * 2;
        }
        float length = fmaxf(end - start + 1.0f, 1.0f);
        float step = length / (float)(n - 1);
        float coord = start + step * (float)j;
        float valid = (coord >= 0.0f && coord < size) ? 1.0f : 0.0f;
        float lo = fminf(fmaxf(floorf(coord), 0.0f), size - 1.0f);
        int lo_i = (int)lo;
        int hi_i = min(lo_i + 1, (int)size - 1);
        float fr = coord - lo;
        int2 offs; offs.x = lo_i * scale; offs.y = hi_i * scale;
        float2 wts; wts.x = (1.0f - fr) * valid; wts.y = fr * valid;
        if (i < 5)       { s_trow[j] = offs; s_twt[j] = wts; }
        else if (i < 13) { s_yrow[j] = offs; s_ywt[j] = wts; }
        else             { s_xoff[j] = offs; s_xwt[j] = wts; }
    }
    __syncthreads();

    int b = (int)sroi[0];
    int c8 = threadIdx.x & 7;     // half8 lane: 8 lanes x 8 ch = 64 channels
    int slot = threadIdx.x >> 3;  // 0..63 sample slot (full 8x8 plane in one pass)
    const char* fb = (const char*)ft
        + ((size_t)b * (T_ * H_ * W_ * C_) + (size_t)(c0 + c8 * 8)) * 2;

    float* bufs[2] = {scratch, scratch + PLN};
    int cc = threadIdx.x & 63;
    int hh = threadIdx.x >> 6;    // 0..7; hh==7 idle for pooling

    float racc[OT][OW];           // statically indexed (t-loop fully unrolled)
#pragma unroll
    for (int t = 0; t < OT; ++t)
#pragma unroll
        for (int w = 0; w < OW; ++w) racc[t][w] = 0.0f;

    int y = slot >> 3, x = slot & 7;
    int2 yr = s_yrow[y]; float2 yw = s_ywt[y];
    int2 xo = s_xoff[x]; float2 xw = s_xwt[x];
    int o00 = yr.x + xo.x, o01 = yr.x + xo.y;
    int o10 = yr.y + xo.x, o11 = yr.y + xo.y;

#pragma unroll
    for (int t = 0; t < PT; ++t) {
        // ---- compute plane t: 64 samples x 64 channels (8 ch/thread) ----
        int2 tr = s_trow[t];
        float2 tw = s_twt[t];
        h8v q00 = *(const h8v*)(fb + tr.x + o00);
        h8v q01 = *(const h8v*)(fb + tr.x + o01);
        h8v q10 = *(const h8v*)(fb + tr.x + o10);
        h8v q11 = *(const h8v*)(fb + tr.x + o11);
        h8v p00 = *(const h8v*)(fb + tr.y + o00);
        h8v p01 = *(const h8v*)(fb + tr.y + o01);
        h8v p10 = *(const h8v*)(fb + tr.y + o10);
        h8v p11 = *(const h8v*)(fb + tr.y + o11);

        f4v vx00L = xw.x * lo4(q00) + xw.y * lo4(q01);
        f4v vx01L = xw.x * lo4(q10) + xw.y * lo4(q11);
        f4v vx10L = xw.x * lo4(p00) + xw.y * lo4(p01);
        f4v vx11L = xw.x * lo4(p10) + xw.y * lo4(p11);
        f4v vx00H = xw.x * hi4(q00) + xw.y * hi4(q01);
        f4v vx01H = xw.x * hi4(q10) + xw.y * hi4(q11);
        f4v vx10H = xw.x * hi4(p00) + xw.y * hi4(p01);
        f4v vx11H = xw.x * hi4(p10) + xw.y * hi4(p11);
        f4v vL = tw.x * (yw.x * vx00L + yw.y * vx01L)
               + tw.y * (yw.x * vx10L + yw.y * vx11L);
        f4v vH = tw.x * (yw.x * vx00H + yw.y * vx01H)
               + tw.y * (yw.x * vx10H + yw.y * vx11H);

        float* bp = bufs[t & 1];
        {
            float* col = &bp[(c8 * 8) * LROW + slot];
            col[0 * LROW] = vL[0];
            col[1 * LROW] = vL[1];
            col[2 * LROW] = vL[2];
            col[3 * LROW] = vL[3];
            col[4 * LROW] = vH[0];
            col[5 * LROW] = vH[1];
            col[6 * LROW] = vH[2];
            col[7 * LROW] = vH[3];
        }
        __syncthreads();   // single barrier/plane: next write hits other buffer

        // ---- accumulate plane t into racc[t] (dt=0) and racc[t-1] (dt=1) ----
        if (hh < 7) {
            const float* p = &bp[cc * LROW + hh * 8];
            float p2[8];
#pragma unroll
            for (int x2 = 0; x2 < 4; ++x2) {
                f2v a = *(const f2v*)(p + 2 * x2);
                f2v bq = *(const f2v*)(p + 8 + 2 * x2);
                f2v s = a + bq;           // y-pool (rows hh, hh+1)
                p2[2 * x2] = s[0];
                p2[2 * x2 + 1] = s[1];
            }
#pragma unroll
            for (int w = 0; w < OW; ++w) {
                float pw = p2[w] + p2[w + 1];   // x-pool
                if (t < OT) racc[t][w] += pw;
                if (t > 0) racc[t - 1][w] += pw;
            }
        }
    }
    __syncthreads();  // plane dbuf dead; scratch reused for flush

    // ---- stage pooled outputs in (c,t,h,w) order, flush coalesced ----
    if (hh < 7) {
        int base = cc * (OT * OH * OW) + hh * OW;
#pragma unroll
        for (int t = 0; t < OT; ++t)
#pragma unroll
            for (int w = 0; w < OW; ++w)
                scratch[base + t * (OH * OW) + w] = racc[t][w] * 0.125f;
    }
    __syncthreads();

    float* outb = out + ((size_t)r * C_ + c0) * (OT * OH * OW);
    const f4v* s4 = (const f4v*)scratch;
    f4v* o4 = (f4v*)outb;
#pragma unroll
    for (int k = 0; k < 7; ++k) {
        int idx = k * 512 + threadIdx.x;
        if (idx < NOUT / 4) __builtin_nontemporal_store(s4[idx], &o4[idx]);
    }
}

// ---------------- fallback: direct gather, one thread per output ----------------
__device__ __forceinline__ void axis_sample(float start, float end, float size, int n,
                                            int j, int& lo_i, int& hi_i, float& frac,
                                            float& valid) {
    float length = fmaxf(end - start + 1.0f, 1.0f);
    float step = length / (float)(n - 1);
    float coord = start + step * (float)j;
    valid = (coord >= 0.0f && coord < size) ? 1.0f : 0.0f;
    float lo = fminf(fmaxf(floorf(coord), 0.0f), size - 1.0f);
    frac = coord - lo;
    lo_i = (int)lo;
    hi_i = min(lo_i + 1, (int)size - 1);
}

__global__ void roi_direct(const float* __restrict__ f, const float* __restrict__ rois,
                           float* __restrict__ out, long long total) {
    long long idx = (long long)blockIdx.x * 256 + threadIdx.x;
    if (idx >= total) return;
    int w = (int)(idx % OW);
    long long q = idx / OW;
    int h = (int)(q % OH);
    q /= OH;
    int t = (int)(q % OT);
    q /= OT;
    int c = (int)(q % C_);
    int r = (int)(q / C_);

    float rb = rois[r * 7 + 0];
    float x1 = rois[r * 7 + 1] * SSCALE;
    float y1 = rois[r * 7 + 2] * SSCALE;
    float x2 = rois[r * 7 + 3] * SSCALE;
    float y2 = rois[r * 7 + 4] * SSCALE;
    float t1 = rois[r * 7 + 5] * TSCALE;
    float t2 = rois[r * 7 + 6] * TSCALE;
    int b = (int)rb;
    const float* fc = f + ((size_t)b * C_ + c) * (T_ * H_ * W_);

    float acc = 0.0f;
    for (int dt = 0; dt < 2; ++dt) {
        int tlo, thi; float tf, tv;
        axis_sample(t1, t2, (float)T_, PT, t + dt, tlo, thi, tf, tv);
        for (int dh = 0; dh < 2; ++dh) {
            int ylo, yhi; float yf, yv;
            axis_sample(y1, y2, (float)H_, PH, h + dh, ylo, yhi, yf, yv);
            for (int dw = 0; dw < 2; ++dw) {
                int xlo, xhi; float xf, xv;
                axis_sample(x1, x2, (float)W_, PW, w + dw, xlo, xhi, xf, xv);
                float v000 = fc[(tlo * H_ + ylo) * W_ + xlo];
                float v001 = fc[(tlo * H_ + ylo) * W_ + xhi];
                float v010 = fc[(tlo * H_ + yhi) * W_ + xlo];
                float v011 = fc[(tlo * H_ + yhi) * W_ + xhi];
                float v100 = fc[(thi * H_ + ylo) * W_ + xlo];
                float v101 = fc[(thi * H_ + ylo) * W_ + xhi];
                float v110 = fc[(thi * H_ + yhi) * W_ + xlo];
                float v111 = fc[(thi * H_ + yhi) * W_ + xhi];
                float vx00 = v000 + xf * (v001 - v000);
                float vx01 = v010 + xf * (v011 - v010);
                float vx10 = v100 + xf * (v101 - v100);
                float vx11 = v110 + xf * (v111 - v110);
                float vy0 = vx00 + yf * (vx01 - vx00);
                float vy1 = vx10 + yf * (vx11 - vx10);
                float v = vy0 + tf * (vy1 - vy0);
                acc += v * (tv * yv * xv);
            }
        }
    }
    out[idx] = acc * 0.125f;
}

extern "C" void kernel_launch(void* const* d_in, const int* in_sizes, int n_in,
                              void* d_out, int out_size, void* d_ws, size_t ws_size,
                              hipStream_t stream) {
    const float* feat = (const float*)d_in[0];
    const float* rois = (const float*)d_in[1];
    float* out = (float*)d_out;
    int nroi = in_sizes[1] / 7;
    int B = in_sizes[0] / (C_ * T_ * H_ * W_);
    size_t ftbytes = (size_t)B * T_ * H_ * W_ * C_ * sizeof(_Float16);
    size_t need = ftbytes + 2048 * sizeof(int);

    if (ws_size >= need && nroi >= 1) {
        _Float16* ft = (_Float16*)d_ws;
        int* perm = (int*)((char*)d_ws + ftbytes);
        sort_rois<<<1, 1024, 0, stream>>>(rois, nroi, perm);
        dim3 g1(T_ * H_ * W_ / 64, B);
        transpose_kernel<<<g1, 256, 0, stream>>>(feat, ft);
        roi_kernel<<<dim3(nroi * (C_ / CG)), 512, 0, stream>>>(ft, rois, perm, out);
    } else {
        long long total = (long long)nroi * C_ * OT * OH * OW;
        roi_direct<<<(int)((total + 255) / 256), 256, 0, stream>>>(feat, rois, out, total);
    }
}

// Round 9
// 515.859 us; speedup vs baseline: 1.1148x; 1.0161x over previous
//
#include <hip/hip_runtime.h>

#define C_ 256
#define T_ 16
#define H_ 64
#define W_ 64
#define PT 5
#define PH 8
#define PW 8
#define OT 4
#define OH 7
#define OW 7
#define SSCALE (1.0f/16.0f)
#define TSCALE 1.0f
#define CG 64               /* channels per roi block */
#define LROW 66             /* plane col stride: 8B-aligned f2v pool reads */
#define PLN (CG * LROW)     /* 4224 floats per plane buffer */
#define NOUT (CG * OT * OH * OW)   /* 12544 outputs per block */

typedef float f4v __attribute__((ext_vector_type(4)));
typedef float f2v __attribute__((ext_vector_type(2)));
typedef _Float16 h2v __attribute__((ext_vector_type(2)));
typedef _Float16 h8v __attribute__((ext_vector_type(8)));

__device__ __forceinline__ f4v lo4(h8v h) {
    f4v r = {(float)h[0], (float)h[1], (float)h[2], (float)h[3]};
    return r;
}
__device__ __forceinline__ f4v hi4(h8v h) {
    f4v r = {(float)h[4], (float)h[5], (float)h[6], (float)h[7]};
    return r;
}

// ---------------- transpose+cvt (B,C,T,H,W) f32 -> (B,T,H,W,C) fp16 ----------------
// At BW roofline (~640 MB): channel-pair packed u32 LDS tile, XOR swizzle,
// coalesced 256B NT reads, full 512B ft line stores.
__global__ __launch_bounds__(256) void transpose_kernel(const float* __restrict__ f,
                                                        _Float16* __restrict__ ft) {
    __shared__ unsigned tile[64 * 128];   // 32 KB
    const int THW = T_ * H_ * W_;
    int thw0 = blockIdx.x * 64;
    int b = blockIdx.y;
    int q = threadIdx.x & 15;      // thw quad
    int cp0 = threadIdx.x >> 4;    // 0..15

#pragma unroll
    for (int k = 0; k < 8; ++k) {
        int cp = k * 16 + cp0;     // channel pair 0..127
        int c = cp * 2;
        const f4v* s0 = reinterpret_cast<const f4v*>(
            &f[((size_t)b * C_ + c) * THW + thw0 + q * 4]);
        const f4v* s1 = reinterpret_cast<const f4v*>(
            &f[((size_t)b * C_ + c + 1) * THW + thw0 + q * 4]);
        f4v va = __builtin_nontemporal_load(s0);
        f4v vb = __builtin_nontemporal_load(s1);
#pragma unroll
        for (int j = 0; j < 4; ++j) {
            int row = q * 4 + j;
            h2v hp = {(_Float16)va[j], (_Float16)vb[j]};
            tile[row * 128 + (cp ^ (row & 30))] = __builtin_bit_cast(unsigned, hp);
        }
    }
    __syncthreads();

    int wv = threadIdx.x >> 6;     // wave 0..3
    int ln = threadIdx.x & 63;
    size_t orow = ((size_t)b * THW + thw0) * C_;
#pragma unroll
    for (int i = 0; i < 16; ++i) {
        int row = wv * 16 + i;
        int s = row & 30;          // even -> pair-preserving XOR -> b64 read
        uint2 w = *reinterpret_cast<const uint2*>(&tile[row * 128 + ((ln * 2) ^ s)]);
        *reinterpret_cast<uint2*>(&ft[orow + (size_t)row * C_ + ln * 4]) = w;
    }
}

// ---------------- spatial roi sort (Morton order) -> perm ----------------
__global__ __launch_bounds__(1024) void sort_rois(const float* __restrict__ rois,
                                                  int nroi, int* __restrict__ perm) {
    __shared__ unsigned key[2048];
    int t = threadIdx.x;
    if (nroi > 2048) {             // fallback: identity order
        for (int i = t; i < nroi; i += 1024) perm[i] = i;
        return;
    }
    for (int i = t; i < 2048; i += 1024) {
        unsigned k = 0x1FFFFFu;    // pad key sorts to end
        if (i < nroi) {
            const float* rp = rois + i * 7;
            int bb = (int)rp[0];
            float xc = (rp[1] + rp[3]) * 0.5f * SSCALE;
            float yc = (rp[2] + rp[4]) * 0.5f * SSCALE;
            float tc = (rp[5] + rp[6]) * 0.5f * TSCALE;
            int xq = min(63, max(0, (int)xc));
            int yq = min(63, max(0, (int)yc));
            int tq = min(15, max(0, (int)tc));
            unsigned m = 0;
#pragma unroll
            for (int bit = 0; bit < 6; ++bit)
                m |= (((yq >> bit) & 1u) << (2 * bit + 1)) |
                     (((xq >> bit) & 1u) << (2 * bit));
            k = ((((unsigned)bb << 12) | m) << 4) | (unsigned)tq;   // 18 bits
        }
        key[i] = (k << 11) | (unsigned)i;
    }
    __syncthreads();
    for (int kk = 2; kk <= 2048; kk <<= 1) {
        for (int j = kk >> 1; j > 0; j >>= 1) {
            for (int i = t; i < 2048; i += 1024) {
                int ixj = i ^ j;
                if (ixj > i) {
                    unsigned a = key[i], c = key[ixj];
                    bool up = (i & kk) == 0;
                    if ((a > c) == up) { key[i] = c; key[ixj] = a; }
                }
            }
            __syncthreads();
        }
    }
    for (int i = t; i < 2048; i += 1024)
        if (i < nroi) perm[i] = (int)(key[i] & 0x7FFu);
}

// ---------------- main: one 512-thread block per (sorted roi, 64-channel group) ----
// roi is LOAD-ISSUE-bound (40 vmem/thread = 160us floor). Fix: rolling 2-entry
// row-plane cache. Consecutive t-planes share t-rows (monotone t samples); the
// xy-interpolated row-plane is cached in registers, so a reused row costs zero
// loads. Loads/thread drop 40 -> ~16-24. Arithmetic order identical to before.
__global__ __launch_bounds__(512) void roi_kernel(const _Float16* __restrict__ ft,
                                                  const float* __restrict__ rois,
                                                  const int* __restrict__ perm,
                                                  float* __restrict__ out) {
    __shared__ float scratch[NOUT];  // 50176 B; first 2*4224 floats = plane dbuf
    __shared__ float sroi[7];
    __shared__ int2 s_trow[PT]; __shared__ float2 s_twt[PT];
    __shared__ int2 s_yrow[PH]; __shared__ float2 s_ywt[PH];
    __shared__ int2 s_xoff[PW]; __shared__ float2 s_xwt[PW];

    int bid = blockIdx.x;
    int r = perm[bid >> 2];
    int cg = bid & 3;
    int c0 = cg * CG;

    if (threadIdx.x < 7) sroi[threadIdx.x] = rois[r * 7 + threadIdx.x];
    __syncthreads();

    // axis tables: byte offsets (lo/hi) + validity-folded weights
    if (threadIdx.x < 21) {
        int i = threadIdx.x;
        float start, end, size;
        int j, n, scale;
        if (i < 5) {
            j = i; n = PT;
            start = sroi[5] * TSCALE; end = sroi[6] * TSCALE;
            size = (float)T_; scale = H_ * W_ * C_ * 2;
        } else if (i < 13) {
            j = i - 5; n = PH;
            start = sroi[2] * SSCALE; end = sroi[4] * SSCALE;
            size = (float)H_; scale = W_ * C_ * 2;
        } else {
            j = i - 13; n = PW;
            start = sroi[1] * SSCALE; end = sroi[3] * SSCALE;
            size = (float)W_; scale = C_ * 2;
        }
        float length = fmaxf(end - start + 1.0f, 1.0f);
        float step = length / (float)(n - 1);
        float coord = start + step * (float)j;
        float valid = (coord >= 0.0f && coord < size) ? 1.0f : 0.0f;
        float lo = fminf(fmaxf(floorf(coord), 0.0f), size - 1.0f);
        int lo_i = (int)lo;
        int hi_i = min(lo_i + 1, (int)size - 1);
        float fr = coord - lo;
        int2 offs; offs.x = lo_i * scale; offs.y = hi_i * scale;
        float2 wts; wts.x = (1.0f - fr) * valid; wts.y = fr * valid;
        if (i < 5)       { s_trow[j] = offs; s_twt[j] = wts; }
        else if (i < 13) { s_yrow[j] = offs; s_ywt[j] = wts; }
        else             { s_xoff[j] = offs; s_xwt[j] = wts; }
    }
    __syncthreads();

    int b = (int)sroi[0];
    int c8 = threadIdx.x & 7;     // half8 lane: 8 lanes x 8 ch = 64 channels
    int slot = threadIdx.x >> 3;  // 0..63 sample slot
    const char* fb = (const char*)ft
        + ((size_t)b * (T_ * H_ * W_ * C_) + (size_t)(c0 + c8 * 8)) * 2;

    float* bufs[2] = {scratch, scratch + PLN};
    int cc = threadIdx.x & 63;
    int hh = threadIdx.x >> 6;    // 0..7; hh==7 idle for pooling

    float racc[OT][OW];
#pragma unroll
    for (int t = 0; t < OT; ++t)
#pragma unroll
        for (int w = 0; w < OW; ++w) racc[t][w] = 0.0f;

    int y = slot >> 3, x = slot & 7;
    int2 yr = s_yrow[y]; float2 yw = s_ywt[y];
    int2 xo = s_xoff[x]; float2 xw = s_xwt[x];
    int o00 = yr.x + xo.x, o01 = yr.x + xo.y;
    int o10 = yr.y + xo.x, o11 = yr.y + xo.y;

    // rolling row-plane cache: slot A (row ia), slot B (row ib)
    int ia = -1, ib = -1;
    f4v aL, aH, bL, bH;
    aL = aH = bL = bH = (f4v){0.f, 0.f, 0.f, 0.f};

#pragma unroll
    for (int t = 0; t < PT; ++t) {
        int2 trv = s_trow[t];
        // block-uniform values -> scalar branches
        int trx = __builtin_amdgcn_readfirstlane(trv.x);
        int trY = __builtin_amdgcn_readfirstlane(trv.y);
        float2 tw = s_twt[t];

        if (ia != trx) {
            if (ib == trx) { aL = bL; aH = bH; ia = trx; }
            else {
                h8v q00 = *(const h8v*)(fb + trx + o00);
                h8v q01 = *(const h8v*)(fb + trx + o01);
                h8v q10 = *(const h8v*)(fb + trx + o10);
                h8v q11 = *(const h8v*)(fb + trx + o11);
                aL = yw.x * (xw.x * lo4(q00) + xw.y * lo4(q01))
                   + yw.y * (xw.x * lo4(q10) + xw.y * lo4(q11));
                aH = yw.x * (xw.x * hi4(q00) + xw.y * hi4(q01))
                   + yw.y * (xw.x * hi4(q10) + xw.y * hi4(q11));
                ia = trx;
            }
        }
        if (ib != trY) {
            if (ia == trY) { bL = aL; bH = aH; ib = trY; }
            else {
                h8v p00 = *(const h8v*)(fb + trY + o00);
                h8v p01 = *(const h8v*)(fb + trY + o01);
                h8v p10 = *(const h8v*)(fb + trY + o10);
                h8v p11 = *(const h8v*)(fb + trY + o11);
                bL = yw.x * (xw.x * lo4(p00) + xw.y * lo4(p01))
                   + yw.y * (xw.x * lo4(p10) + xw.y * lo4(p11));
                bH = yw.x * (xw.x * hi4(p00) + xw.y * hi4(p01))
                   + yw.y * (xw.x * hi4(p10) + xw.y * hi4(p11));
                ib = trY;
            }
        }

        f4v vL = tw.x * aL + tw.y * bL;
        f4v vH = tw.x * aH + tw.y * bH;

        float* bp = bufs[t & 1];
        {
            float* col = &bp[(c8 * 8) * LROW + slot];
            col[0 * LROW] = vL[0];
            col[1 * LROW] = vL[1];
            col[2 * LROW] = vL[2];
            col[3 * LROW] = vL[3];
            col[4 * LROW] = vH[0];
            col[5 * LROW] = vH[1];
            col[6 * LROW] = vH[2];
            col[7 * LROW] = vH[3];
        }
        __syncthreads();   // single barrier/plane: next write hits other buffer

        // ---- accumulate plane t into racc[t] (dt=0) and racc[t-1] (dt=1) ----
        if (hh < 7) {
            const float* p = &bp[cc * LROW + hh * 8];
            float p2[8];
#pragma unroll
            for (int x2 = 0; x2 < 4; ++x2) {
                f2v a = *(const f2v*)(p + 2 * x2);
                f2v bq = *(const f2v*)(p + 8 + 2 * x2);
                f2v s = a + bq;           // y-pool (rows hh, hh+1)
                p2[2 * x2] = s[0];
                p2[2 * x2 + 1] = s[1];
            }
#pragma unroll
            for (int w = 0; w < OW; ++w) {
                float pw = p2[w] + p2[w + 1];   // x-pool
                if (t < OT) racc[t][w] += pw;
                if (t > 0) racc[t - 1][w] += pw;
            }
        }
    }
    __syncthreads();  // plane dbuf dead; scratch reused for flush

    // ---- stage pooled outputs in (c,t,h,w) order, flush coalesced ----
    if (hh < 7) {
        int base = cc * (OT * OH * OW) + hh * OW;
#pragma unroll
        for (int t = 0; t < OT; ++t)
#pragma unroll
            for (int w = 0; w < OW; ++w)
                scratch[base + t * (OH * OW) + w] = racc[t][w] * 0.125f;
    }
    __syncthreads();

    float* outb = out + ((size_t)r * C_ + c0) * (OT * OH * OW);
    const f4v* s4 = (const f4v*)scratch;
    f4v* o4 = (f4v*)outb;
#pragma unroll
    for (int k = 0; k < 7; ++k) {
        int idx = k * 512 + threadIdx.x;
        if (idx < NOUT / 4) __builtin_nontemporal_store(s4[idx], &o4[idx]);
    }
}

// ---------------- fallback: direct gather, one thread per output ----------------
__device__ __forceinline__ void axis_sample(float start, float end, float size, int n,
                                            int j, int& lo_i, int& hi_i, float& frac,
                                            float& valid) {
    float length = fmaxf(end - start + 1.0f, 1.0f);
    float step = length / (float)(n - 1);
    float coord = start + step * (float)j;
    valid = (coord >= 0.0f && coord < size) ? 1.0f : 0.0f;
    float lo = fminf(fmaxf(floorf(coord), 0.0f), size - 1.0f);
    frac = coord - lo;
    lo_i = (int)lo;
    hi_i = min(lo_i + 1, (int)size - 1);
}

__global__ void roi_direct(const float* __restrict__ f, const float* __restrict__ rois,
                           float* __restrict__ out, long long total) {
    long long idx = (long long)blockIdx.x * 256 + threadIdx.x;
    if (idx >= total) return;
    int w = (int)(idx % OW);
    long long q = idx / OW;
    int h = (int)(q % OH);
    q /= OH;
    int t = (int)(q % OT);
    q /= OT;
    int c = (int)(q % C_);
    int r = (int)(q / C_);

    float rb = rois[r * 7 + 0];
    float x1 = rois[r * 7 + 1] * SSCALE;
    float y1 = rois[r * 7 + 2] * SSCALE;
    float x2 = rois[r * 7 + 3] * SSCALE;
    float y2 = rois[r * 7 + 4] * SSCALE;
    float t1 = rois[r * 7 + 5] * TSCALE;
    float t2 = rois[r * 7 + 6] * TSCALE;
    int b = (int)rb;
    const float* fc = f + ((size_t)b * C_ + c) * (T_ * H_ * W_);

    float acc = 0.0f;
    for (int dt = 0; dt < 2; ++dt) {
        int tlo, thi; float tf, tv;
        axis_sample(t1, t2, (float)T_, PT, t + dt, tlo, thi, tf, tv);
        for (int dh = 0; dh < 2; ++dh) {
            int ylo, yhi; float yf, yv;
            axis_sample(y1, y2, (float)H_, PH, h + dh, ylo, yhi, yf, yv);
            for (int dw = 0; dw < 2; ++dw) {
                int xlo, xhi; float xf, xv;
                axis_sample(x1, x2, (float)W_, PW, w + dw, xlo, xhi, xf, xv);
                float v000 = fc[(tlo * H_ + ylo) * W_ + xlo];
                float v001 = fc[(tlo * H_ + ylo) * W_ + xhi];
                float v010 = fc[(tlo * H_ + yhi) * W_ + xlo];
                float v011 = fc[(tlo * H_ + yhi) * W_ + xhi];
                float v100 = fc[(thi * H_ + ylo) * W_ + xlo];
                float v101 = fc[(thi * H_ + ylo) * W_ + xhi];
                float v110 = fc[(thi * H_ + yhi) * W_ + xlo];
                float v111 = fc[(thi * H_ + yhi) * W_ + xhi];
                float vx00 = v000 + xf * (v001 - v000);
                float vx01 = v010 + xf * (v011 - v010);
                float vx10 = v100 + xf * (v101 - v100);
                float vx11 = v110 + xf * (v111 - v110);
                float vy0 = vx00 + yf * (vx01 - vx00);
                float vy1 = vx10 + yf * (vx11 - vx10);
                float v = vy0 + tf * (vy1 - vy0);
                acc += v * (tv * yv * xv);
            }
        }
    }
    out[idx] = acc * 0.125f;
}

extern "C" void kernel_launch(void* const* d_in, const int* in_sizes, int n_in,
                              void* d_out, int out_size, void* d_ws, size_t ws_size,
                              hipStream_t stream) {
    const float* feat = (const float*)d_in[0];
    const float* rois = (const float*)d_in[1];
    float* out = (float*)d_out;
    int nroi = in_sizes[1] / 7;
    int B = in_sizes[0] / (C_ * T_ * H_ * W_);
    size_t ftbytes = (size_t)B * T_ * H_ * W_ * C_ * sizeof(_Float16);
    size_t need = ftbytes + 2048 * sizeof(int);

    if (ws_size >= need && nroi >= 1) {
        _Float16* ft = (_Float16*)d_ws;
        int* perm = (int*)((char*)d_ws + ftbytes);
        sort_rois<<<1, 1024, 0, stream>>>(rois, nroi, perm);
        dim3 g1(T_ * H_ * W_ / 64, B);
        transpose_kernel<<<g1, 256, 0, stream>>>(feat, ft);
        roi_kernel<<<dim3(nroi * (C_ / CG)), 512, 0, stream>>>(ft, rois, perm, out);
    } else {
        long long total = (long long)nroi * C_ * OT * OH * OW;
        roi_direct<<<(int)((total + 255) / 256), 256, 0, stream>>>(feat, rois, out, total);
    }
}